// Round 6
// baseline (555.131 us; speedup 1.0000x reference)
//
#include <hip/hip_runtime.h>
#include <hip/hip_bf16.h>
#include <stdint.h>

// ---------- types ----------
typedef __attribute__((ext_vector_type(8))) __bf16 bf16x8;
typedef __attribute__((ext_vector_type(8))) short short8v;
typedef __attribute__((ext_vector_type(4))) short short4v;
typedef __attribute__((ext_vector_type(4))) float f32x4;

__device__ __forceinline__ float bf2f(short u) {
  return __builtin_bit_cast(float, (uint32_t)((uint32_t)(uint16_t)u << 16));
}
__device__ __forceinline__ short f2bf(float f) {
  uint32_t x = __builtin_bit_cast(uint32_t, f);
  x += 0x7FFFu + ((x >> 16) & 1u);
  return (short)(x >> 16);
}
// D = A*B + C. TRANSPOSED convention everywhere: A = weight frag (A[m=f][k]),
// B = h-row frag (B[k][n=row]); D: lane ll = row, regs quad*4+r = 4 consecutive features.
__device__ __forceinline__ f32x4 mfma16(short8v a, short8v b, f32x4 c) {
  return __builtin_amdgcn_mfma_f32_16x16x32_bf16(
      __builtin_bit_cast(bf16x8, a), __builtin_bit_cast(bf16x8, b), c, 0, 0, 0);
}
// XOR-swizzled LDS address (shorts), 16B-chunk swizzle.
__device__ __forceinline__ int swz256(int row, int col) {
  return row * 256 + (col ^ ((row & 7) << 3));
}
__device__ __forceinline__ int swz128(int row, int col) {
  return row * 128 + (col ^ ((row & 7) << 3));
}

// ---------- merged prepack: all 11 weights in ONE launch ----------
// dst per weight: [nt][kt][lane][8 bf16]; W[k=kt*32+(lane>>4)*8+j][n=nt*16+(lane&15)]
// Serves as the A-operand fragment (A[m=n][k]) in the transposed convention.
struct PPDesc { const float* src; short* dst; int Ks, Ns, KT, NT, tile_base; };
struct PPArgs { PPDesc d[11]; int n_desc; int total_tiles; };

__global__ void prepack_all(PPArgs args) {
  int idx = blockIdx.x * 256 + threadIdx.x;
  int tile = idx >> 6;
  if (tile >= args.total_tiles) return;
  int lane = idx & 63;
  int e = 0;
  while (e + 1 < args.n_desc && args.d[e + 1].tile_base <= tile) ++e;
  const PPDesc D = args.d[e];
  int t = tile - D.tile_base;
  int kt = t % D.KT, nt = t / D.KT;
  int n = nt * 16 + (lane & 15);
  int kbase = kt * 32 + ((lane >> 4) * 8);
  short8v o;
#pragma unroll
  for (int j = 0; j < 8; ++j) {
    int k = kbase + j;
    o[j] = f2bf((k < D.Ks && n < D.Ns) ? D.src[k * D.Ns + n] : 0.f);
  }
  *(short8v*)&D.dst[((size_t)t * 64 + lane) * 8] = o;
}

// ---------- qb[b,c] = qst[b] @ Wg1[200:211] + bg1 (32 batches/block) ----------
__global__ void qb_kernel(const float* __restrict__ qst, const float* __restrict__ Wg1,
                          const float* __restrict__ bg1, float* __restrict__ qb) {
  int c = threadIdx.x;
  int b0 = blockIdx.x * 32;
  float wcol[11];
#pragma unroll
  for (int k = 0; k < 11; ++k) wcol[k] = Wg1[(200 + k) * 256 + c];
  float bias = bg1[c];
#pragma unroll 1
  for (int bb = 0; bb < 32; ++bb) {
    int b = b0 + bb;
    float acc = bias;
#pragma unroll
    for (int k = 0; k < 11; ++k) acc += qst[b * 11 + k] * wcol[k];
    qb[b * 256 + c] = acc;
  }
}

// ---------- encoder: tabs[64 rows x 10] -> x -> u,v (bf16, [obj][256]) ----------
__launch_bounds__(256, 3)
__global__ void enc_kernel(const float* __restrict__ tabs,
    const float* __restrict__ bi1, const float* __restrict__ bi2, const float* __restrict__ bi3,
    const short* __restrict__ Wi1p, const short* __restrict__ Wi2p, const short* __restrict__ Wi3p,
    const short* __restrict__ Wap, const short* __restrict__ Wbp,
    short* __restrict__ u_g, short* __restrict__ v_g) {
  __shared__ __align__(16) short sIn[64 * 40];   // K padded 10->32, stride 40 (16B-aligned rows)
  __shared__ __align__(16) short sH1[64 * 256];  // swizzled; sX aliases after L2
  __shared__ __align__(16) short sH2[64 * 128];  // swizzled
  short* sX = sH1;
  const int tid = threadIdx.x;
  const int lane = tid & 63, w = tid >> 6, quad = lane >> 4, ll = lane & 15;
  const int xl = (ll & 7) << 3;
  const int obj0 = blockIdx.x * 64;

  for (int idx = tid; idx < 64 * 40; idx += 256) {
    int r = idx / 40, k = idx - r * 40;
    float v = (k < 10) ? tabs[(obj0 + r) * 10 + k] : 0.f;
    sIn[idx] = f2bf(v);
  }
  __syncthreads();

  // L1: K=32(pad), out 256. Wave owns 4 f-tiles, 4 obj-tiles.
  {
    f32x4 acc[4][4] = {};
    short8v bIn[4];
#pragma unroll
    for (int mt = 0; mt < 4; ++mt)
      bIn[mt] = *(const short8v*)&sIn[(mt * 16 + ll) * 40 + quad * 8];
#pragma unroll
    for (int ni = 0; ni < 4; ++ni) {
      short8v wf = *(const short8v*)&Wi1p[((w * 4 + ni) * 64 + lane) * 8];
#pragma unroll
      for (int mt = 0; mt < 4; ++mt) acc[mt][ni] = mfma16(wf, bIn[mt], acc[mt][ni]);
    }
#pragma unroll
    for (int ni = 0; ni < 4; ++ni) {
      int fbase = (w * 4 + ni) * 16 + quad * 4;
      f32x4 b4 = *(const f32x4*)&bi1[fbase];
#pragma unroll
      for (int mt = 0; mt < 4; ++mt) {
        int row = mt * 16 + ll;
        short4v o;
#pragma unroll
        for (int r = 0; r < 4; ++r) o[r] = f2bf(fmaxf(acc[mt][ni][r] + b4[r], 0.f));
        *(short4v*)&sH1[swz256(row, fbase)] = o;
      }
    }
  }
  __syncthreads();

  // L2: K=256, out 128. Wave owns 2 f-tiles.
  {
    f32x4 acc[4][2] = {};
#pragma unroll 1
    for (int kt = 0; kt < 8; ++kt) {
      short8v wf[2];
#pragma unroll
      for (int ni = 0; ni < 2; ++ni)
        wf[ni] = *(const short8v*)&Wi2p[(((w * 2 + ni) * 8 + kt) * 64 + lane) * 8];
#pragma unroll
      for (int mt = 0; mt < 4; ++mt) {
        short8v h = *(const short8v*)&sH1[(mt * 16 + ll) * 256 + ((kt * 32 + quad * 8) ^ xl)];
#pragma unroll
        for (int ni = 0; ni < 2; ++ni) acc[mt][ni] = mfma16(wf[ni], h, acc[mt][ni]);
      }
    }
    __syncthreads();   // sH1 reads done (sX aliases it)
#pragma unroll
    for (int ni = 0; ni < 2; ++ni) {
      int fbase = (w * 2 + ni) * 16 + quad * 4;
      f32x4 b4 = *(const f32x4*)&bi2[fbase];
#pragma unroll
      for (int mt = 0; mt < 4; ++mt) {
        int row = mt * 16 + ll;
        short4v o;
#pragma unroll
        for (int r = 0; r < 4; ++r) o[r] = f2bf(fmaxf(acc[mt][ni][r] + b4[r], 0.f));
        *(short4v*)&sH2[swz128(row, fbase)] = o;
      }
    }
  }
  __syncthreads();

  // L3: K=128, out 128 (cols>=100 zero), NO relu -> sX
  {
    f32x4 acc[4][2] = {};
#pragma unroll 1
    for (int kt = 0; kt < 4; ++kt) {
      short8v wf[2];
#pragma unroll
      for (int ni = 0; ni < 2; ++ni)
        wf[ni] = *(const short8v*)&Wi3p[(((w * 2 + ni) * 4 + kt) * 64 + lane) * 8];
#pragma unroll
      for (int mt = 0; mt < 4; ++mt) {
        short8v h = *(const short8v*)&sH2[(mt * 16 + ll) * 128 + ((kt * 32 + quad * 8) ^ xl)];
#pragma unroll
        for (int ni = 0; ni < 2; ++ni) acc[mt][ni] = mfma16(wf[ni], h, acc[mt][ni]);
      }
    }
#pragma unroll
    for (int ni = 0; ni < 2; ++ni) {
      int fbase = (w * 2 + ni) * 16 + quad * 4;
#pragma unroll
      for (int mt = 0; mt < 4; ++mt) {
        int row = mt * 16 + ll;
        short4v o;
#pragma unroll
        for (int r = 0; r < 4; ++r) {
          int f = fbase + r;
          float vv = (f < 100) ? (acc[mt][ni][r] + bi3[f]) : 0.f;
          o[r] = f2bf(vv);
        }
        *(short4v*)&sX[swz128(row, fbase)] = o;
      }
    }
  }
  __syncthreads();

  // L4: u = x @ Wa ; v = x @ Wb  K=128, out 256 each, no bias/relu
#pragma unroll 1
  for (int pass = 0; pass < 2; ++pass) {
    const short* Wp = pass ? Wbp : Wap;
    short* outg = pass ? v_g : u_g;
    f32x4 acc[4][4] = {};
#pragma unroll 1
    for (int kt = 0; kt < 4; ++kt) {
      short8v wf[4];
#pragma unroll
      for (int ni = 0; ni < 4; ++ni)
        wf[ni] = *(const short8v*)&Wp[(((w * 4 + ni) * 4 + kt) * 64 + lane) * 8];
#pragma unroll
      for (int mt = 0; mt < 4; ++mt) {
        short8v h = *(const short8v*)&sX[(mt * 16 + ll) * 128 + ((kt * 32 + quad * 8) ^ xl)];
#pragma unroll
        for (int ni = 0; ni < 4; ++ni) acc[mt][ni] = mfma16(wf[ni], h, acc[mt][ni]);
      }
    }
#pragma unroll
    for (int ni = 0; ni < 4; ++ni) {
      int fbase = (w * 4 + ni) * 16 + quad * 4;
#pragma unroll
      for (int mt = 0; mt < 4; ++mt) {
        int obj = obj0 + mt * 16 + ll;
        short4v o;
#pragma unroll
        for (int r = 0; r < 4; ++r) o[r] = f2bf(acc[mt][ni][r]);
        *(short4v*)&outg[(size_t)obj * 256 + fbase] = o;   // 8B coalesced store
      }
    }
  }
}

// ---------- pair MLP: 512 thr (8 waves = 4 f-groups x 2 p-groups), 2 batches/block ----
// Transposed GEMM: D[f][p]. ni=4 f-tiles/wave doubles weight reuse per LDS B-read.
// p-group0: row-tiles 0..2 (rows 0-47), p-group1: tiles 3..4 (rows 48-79, 72+ pad).
__launch_bounds__(512, 4)
__global__ void pair_kernel(const short* __restrict__ u_g, const short* __restrict__ v_g,
    const float* __restrict__ qbp,
    const short* __restrict__ Wg2p, const short* __restrict__ Wg3p, const short* __restrict__ Wg4p,
    const float* __restrict__ bg2, const float* __restrict__ bg3, const float* __restrict__ bg4,
    float* __restrict__ g_g) {
  __shared__ __align__(16) short sH[80 * 256];   // 40,960 B, swizzled
  __shared__ __align__(16) float pool1[256];     // batch-1 partial pool (pg0 -> pg1)
  const int tid = threadIdx.x;
  const int lane = tid & 63, w = tid >> 6, quad = lane >> 4, ll = lane & 15;
  const int xl = (ll & 7) << 3;
  const int fg = w & 3, pg = w >> 2;
  const int MT = pg ? 2 : 3;
  const int mtb = pg ? 3 : 0;
  const int b0 = blockIdx.x * 2;

  if (tid < 256) *(short8v*)&sH[72 * 256 + tid * 8] = short8v{0, 0, 0, 0, 0, 0, 0, 0};

  // h1 = relu(u[j] + v[i] + qb): one 16B chunk per thread; 72 rows x 32 chunks = 2304.
#pragma unroll 1
  for (int it = 0; it < 5; ++it) {
    int vi = it * 512 + tid;
    if (vi < 2304) {
      int row = vi >> 5, c8 = (vi & 31) * 8;
      int bb = row / 36, p = row - bb * 36;
      int i2 = p / 6, j2 = p - i2 * 6;
      short8v u8 = *(const short8v*)&u_g[((b0 + bb) * 6 + j2) * 256 + c8];
      short8v v8 = *(const short8v*)&v_g[((b0 + bb) * 6 + i2) * 256 + c8];
      f32x4 qa = *(const f32x4*)&qbp[(b0 + bb) * 256 + c8];
      f32x4 qc = *(const f32x4*)&qbp[(b0 + bb) * 256 + c8 + 4];
      short8v o;
#pragma unroll
      for (int e = 0; e < 4; ++e)
        o[e] = f2bf(fmaxf(bf2f(u8[e]) + bf2f(v8[e]) + qa[e], 0.f));
#pragma unroll
      for (int e = 0; e < 4; ++e)
        o[4 + e] = f2bf(fmaxf(bf2f(u8[4 + e]) + bf2f(v8[4 + e]) + qc[e], 0.f));
      *(short8v*)&sH[row * 256 + (c8 ^ ((row & 7) << 3))] = o;
    }
  }
  __syncthreads();

#pragma unroll 1
  for (int L = 0; L < 3; ++L) {
    const short* __restrict__ Wp = (L == 0) ? Wg2p : (L == 1) ? Wg3p : Wg4p;
    const float* __restrict__ bp = (L == 0) ? bg2 : (L == 1) ? bg3 : bg4;
    f32x4 acc[3][4] = {};
#pragma unroll 1
    for (int kt = 0; kt < 8; ++kt) {
      short8v wf[4];
#pragma unroll
      for (int ni = 0; ni < 4; ++ni)
        wf[ni] = *(const short8v*)&Wp[(((fg * 4 + ni) * 8 + kt) * 64 + lane) * 8];
#pragma unroll
      for (int mt = 0; mt < 3; ++mt) {
        if (mt < MT) {
          short8v h = *(const short8v*)&sH[((mtb + mt) * 16 + ll) * 256 +
                                           ((kt * 32 + quad * 8) ^ xl)];
#pragma unroll
          for (int ni = 0; ni < 4; ++ni) acc[mt][ni] = mfma16(wf[ni], h, acc[mt][ni]);
        }
      }
    }
    __syncthreads();  // all reads of sH done before in-place overwrite
    if (L < 2) {
#pragma unroll
      for (int ni = 0; ni < 4; ++ni) {
        int fbase = (fg * 4 + ni) * 16 + quad * 4;
        f32x4 b4 = *(const f32x4*)&bp[fbase];
#pragma unroll
        for (int mt = 0; mt < 3; ++mt) {
          if (mt < MT) {
            int p = (mtb + mt) * 16 + ll;
            short4v o;
#pragma unroll
            for (int r = 0; r < 4; ++r) o[r] = f2bf(fmaxf(acc[mt][ni][r] + b4[r], 0.f));
            *(short4v*)&sH[swz256(p, fbase)] = o;   // 8B write, 4x fewer ops
          }
        }
      }
      __syncthreads();
    } else {
      // g4: relu + sum-pool. Lane ll indexes rows -> shfl butterfly over ll.
      f32x4 s1keep[4];
#pragma unroll
      for (int ni = 0; ni < 4; ++ni) {
        int fbase = (fg * 4 + ni) * 16 + quad * 4;
        f32x4 b4 = *(const f32x4*)&bp[fbase];
        f32x4 s0 = {0.f, 0.f, 0.f, 0.f}, s1 = {0.f, 0.f, 0.f, 0.f};
#pragma unroll
        for (int mt = 0; mt < 3; ++mt) {
          if (mt < MT) {
            int p = (mtb + mt) * 16 + ll;
#pragma unroll
            for (int r = 0; r < 4; ++r) {
              float v = fmaxf(acc[mt][ni][r] + b4[r], 0.f);
              if (p < 36) s0[r] += v;
              else if (p < 72) s1[r] += v;
            }
          }
        }
#pragma unroll
        for (int d = 1; d <= 8; d <<= 1) {
#pragma unroll
          for (int r = 0; r < 4; ++r) {
            s0[r] += __shfl_xor(s0[r], d, 64);
            s1[r] += __shfl_xor(s1[r], d, 64);
          }
        }
        s1keep[ni] = s1;
        if (pg == 0 && ll == 0) {
          *(f32x4*)&g_g[(size_t)b0 * 256 + fbase] = s0;      // batch0 fully in pg0
          *(f32x4*)&pool1[fbase] = s1;                        // batch1 partial
        }
      }
      __syncthreads();
      if (pg == 1 && ll == 0) {
#pragma unroll
        for (int ni = 0; ni < 4; ++ni) {
          int fbase = (fg * 4 + ni) * 16 + quad * 4;
          f32x4 t = *(const f32x4*)&pool1[fbase];
#pragma unroll
          for (int r = 0; r < 4; ++r) t[r] += s1keep[ni][r];
          *(f32x4*)&g_g[(size_t)(b0 + 1) * 256 + fbase] = t;
        }
      }
    }
  }
}

// ---------- head helper (transposed): 64x256 @ 256x256 + bias + relu, LDS->LDS ----------
__device__ __forceinline__ void gemm64x256T(const short* sInp, short* sOut,
    const short* __restrict__ Wp, const float* __restrict__ bias,
    int w, int lane, int quad, int ll, int xl) {
  f32x4 acc[4][4] = {};
#pragma unroll 1
  for (int kt = 0; kt < 8; ++kt) {
    short8v wf[4];
#pragma unroll
    for (int ni = 0; ni < 4; ++ni)
      wf[ni] = *(const short8v*)&Wp[(((w * 4 + ni) * 8 + kt) * 64 + lane) * 8];
#pragma unroll
    for (int mt = 0; mt < 4; ++mt) {
      short8v h = *(const short8v*)&sInp[(mt * 16 + ll) * 256 + ((kt * 32 + quad * 8) ^ xl)];
#pragma unroll
      for (int ni = 0; ni < 4; ++ni) acc[mt][ni] = mfma16(wf[ni], h, acc[mt][ni]);
    }
  }
#pragma unroll
  for (int ni = 0; ni < 4; ++ni) {
    int fbase = (w * 4 + ni) * 16 + quad * 4;
    f32x4 b4 = *(const f32x4*)&bias[fbase];
#pragma unroll
    for (int mt = 0; mt < 4; ++mt) {
      int row = mt * 16 + ll;
      short4v o;
#pragma unroll
      for (int r = 0; r < 4; ++r) o[r] = f2bf(fmaxf(acc[mt][ni][r] + b4[r], 0.f));
      *(short4v*)&sOut[swz256(row, fbase)] = o;
    }
  }
}

// ---------- head: g -> f -> o -> logits -> log_softmax ----------
__launch_bounds__(256, 2)
__global__ void head_kernel(const float* __restrict__ g_g,
    const short* __restrict__ Wfp, const float* __restrict__ bf_,
    const short* __restrict__ Wo1p, const float* __restrict__ bo1,
    const short* __restrict__ Wo2p, const float* __restrict__ bo2,
    float* __restrict__ outp) {
  __shared__ __align__(16) short sA[64 * 256];
  __shared__ __align__(16) short sB[64 * 256];
  __shared__ float sL[64 * 16];
  const int tid = threadIdx.x;
  const int lane = tid & 63, w = tid >> 6, quad = lane >> 4, ll = lane & 15;
  const int xl = (ll & 7) << 3;
  const int b0 = blockIdx.x * 64;

#pragma unroll 1
  for (int it = 0; it < 16; ++it) {
    int vi = it * 256 + tid;
    int row = vi >> 6, c4 = (vi & 63) * 4;
    f32x4 gv = *(const f32x4*)&g_g[(b0 + row) * 256 + c4];
    short4v o;
#pragma unroll
    for (int e = 0; e < 4; ++e) o[e] = f2bf(gv[e]);
    *(short4v*)&sA[row * 256 + (c4 ^ ((row & 7) << 3))] = o;
  }
  __syncthreads();
  gemm64x256T(sA, sB, Wfp, bf_, w, lane, quad, ll, xl);
  __syncthreads();
  gemm64x256T(sB, sA, Wo1p, bo1, w, lane, quad, ll, xl);
  __syncthreads();
  {
    // Wo2: D[class][batch]; wave w owns batch tile w; lane ll = batch, regs = classes.
    f32x4 acc = {};
#pragma unroll 1
    for (int kt = 0; kt < 8; ++kt) {
      short8v wf = *(const short8v*)&Wo2p[(kt * 64 + lane) * 8];
      short8v h = *(const short8v*)&sA[(w * 16 + ll) * 256 + ((kt * 32 + quad * 8) ^ xl)];
      acc = mfma16(wf, h, acc);
    }
    f32x4 ov;
#pragma unroll
    for (int r = 0; r < 4; ++r) {
      int cls = quad * 4 + r;
      ov[r] = acc[r] + ((cls < 10) ? bo2[cls] : 0.f);
    }
    *(f32x4*)&sL[(w * 16 + ll) * 16 + quad * 4] = ov;   // b128 store
  }
  __syncthreads();
  if (tid < 64) {
    float m = -1e30f;
#pragma unroll
    for (int c = 0; c < 10; ++c) m = fmaxf(m, sL[tid * 16 + c]);
    float s = 0.f;
#pragma unroll
    for (int c = 0; c < 10; ++c) s += expf(sL[tid * 16 + c] - m);
    float ls = logf(s) + m;
#pragma unroll
    for (int c = 0; c < 10; ++c) outp[(b0 + tid) * 10 + c] = sL[tid * 16 + c] - ls;
  }
}

extern "C" void kernel_launch(void* const* d_in, const int* in_sizes, int n_in,
                              void* d_out, int out_size, void* d_ws, size_t ws_size,
                              hipStream_t stream) {
  const float* tabs = (const float*)d_in[0];
  const float* qst  = (const float*)d_in[1];
  const float* Wi1 = (const float*)d_in[2];  const float* bi1 = (const float*)d_in[3];
  const float* Wi2 = (const float*)d_in[4];  const float* bi2 = (const float*)d_in[5];
  const float* Wi3 = (const float*)d_in[6];  const float* bi3 = (const float*)d_in[7];
  const float* Wg1 = (const float*)d_in[8];  const float* bg1 = (const float*)d_in[9];
  const float* Wg2 = (const float*)d_in[10]; const float* bg2 = (const float*)d_in[11];
  const float* Wg3 = (const float*)d_in[12]; const float* bg3 = (const float*)d_in[13];
  const float* Wg4 = (const float*)d_in[14]; const float* bg4 = (const float*)d_in[15];
  const float* Wf  = (const float*)d_in[16]; const float* bf_ = (const float*)d_in[17];
  const float* Wo1 = (const float*)d_in[18]; const float* bo1 = (const float*)d_in[19];
  const float* Wo2 = (const float*)d_in[20]; const float* bo2 = (const float*)d_in[21];
  float* outp = (float*)d_out;
  (void)in_sizes; (void)n_in; (void)out_size; (void)ws_size;

  char* ws = (char*)d_ws;
  size_t off = 0;
  auto alloc = [&](size_t bytes) { void* p = ws + off; off += (bytes + 255) & ~(size_t)255; return p; };
  const size_t BN = 16384ull * 6;
  short* u_g = (short*)alloc(BN * 256 * 2);
  short* v_g = (short*)alloc(BN * 256 * 2);
  float* qb  = (float*)alloc(16384ull * 256 * 4);
  float* g_g = (float*)alloc(16384ull * 256 * 4);
  short* Wi1p = (short*)alloc(16 * 1 * 64 * 8 * 2);
  short* Wi2p = (short*)alloc(8 * 8 * 64 * 8 * 2);
  short* Wi3p = (short*)alloc(8 * 4 * 64 * 8 * 2);
  short* Wap  = (short*)alloc(16 * 4 * 64 * 8 * 2);
  short* Wbp  = (short*)alloc(16 * 4 * 64 * 8 * 2);
  short* Wg2p = (short*)alloc(16 * 8 * 64 * 8 * 2);
  short* Wg3p = (short*)alloc(16 * 8 * 64 * 8 * 2);
  short* Wg4p = (short*)alloc(16 * 8 * 64 * 8 * 2);
  short* Wfp  = (short*)alloc(16 * 8 * 64 * 8 * 2);
  short* Wo1p = (short*)alloc(16 * 8 * 64 * 8 * 2);
  short* Wo2p = (short*)alloc(1 * 8 * 64 * 8 * 2);

  PPArgs pa;
  int tb = 0, nd = 0;
  auto add = [&](const float* src, short* dst, int Ks, int Ns, int KT, int NT) {
    pa.d[nd++] = PPDesc{src, dst, Ks, Ns, KT, NT, tb};
    tb += KT * NT;
  };
  add(Wi1, Wi1p, 10, 256, 1, 16);
  add(Wi2, Wi2p, 256, 128, 8, 8);
  add(Wi3, Wi3p, 128, 100, 4, 8);
  add(Wg1,             Wap, 100, 256, 4, 16);
  add(Wg1 + 100 * 256, Wbp, 100, 256, 4, 16);
  add(Wg2, Wg2p, 256, 256, 8, 16);
  add(Wg3, Wg3p, 256, 256, 8, 16);
  add(Wg4, Wg4p, 256, 256, 8, 16);
  add(Wf,  Wfp,  256, 256, 8, 16);
  add(Wo1, Wo1p, 256, 256, 8, 16);
  add(Wo2, Wo2p, 256, 10, 8, 1);
  pa.n_desc = nd;
  pa.total_tiles = tb;
  prepack_all<<<(tb * 64 + 255) / 256, 256, 0, stream>>>(pa);

  qb_kernel<<<512, 256, 0, stream>>>(qst, Wg1, bg1, qb);
  enc_kernel<<<1536, 256, 0, stream>>>(tabs, bi1, bi2, bi3, Wi1p, Wi2p, Wi3p, Wap, Wbp, u_g, v_g);
  pair_kernel<<<8192, 512, 0, stream>>>(u_g, v_g, qb, Wg2p, Wg3p, Wg4p, bg2, bg3, bg4, g_g);
  head_kernel<<<256, 256, 0, stream>>>(g_g, Wfp, bf_, Wo1p, bo1, Wo2p, bo2, outp);
}

// Round 8
// 461.988 us; speedup vs baseline: 1.2016x; 1.2016x over previous
//
#include <hip/hip_runtime.h>
#include <hip/hip_bf16.h>
#include <stdint.h>

// ---------- types ----------
typedef __attribute__((ext_vector_type(8))) __bf16 bf16x8;
typedef __attribute__((ext_vector_type(8))) short short8v;
typedef __attribute__((ext_vector_type(4))) short short4v;
typedef __attribute__((ext_vector_type(4))) float f32x4;

__device__ __forceinline__ float bf2f(short u) {
  return __builtin_bit_cast(float, (uint32_t)((uint32_t)(uint16_t)u << 16));
}
__device__ __forceinline__ short f2bf(float f) {
  uint32_t x = __builtin_bit_cast(uint32_t, f);
  x += 0x7FFFu + ((x >> 16) & 1u);
  return (short)(x >> 16);
}
// D = A*B + C. TRANSPOSED convention: A = weight frag (A[m=f][k]),
// B = h-row frag (B[k][n=row]); D: lane ll = row, regs quad*4+r = 4 consecutive f.
__device__ __forceinline__ f32x4 mfma16(short8v a, short8v b, f32x4 c) {
  return __builtin_amdgcn_mfma_f32_16x16x32_bf16(
      __builtin_bit_cast(bf16x8, a), __builtin_bit_cast(bf16x8, b), c, 0, 0, 0);
}
// XOR-swizzled LDS address (shorts), 16B-chunk swizzle.
__device__ __forceinline__ int swz256(int row, int col) {
  return row * 256 + (col ^ ((row & 7) << 3));
}
__device__ __forceinline__ int swz128(int row, int col) {
  return row * 128 + (col ^ ((row & 7) << 3));
}

// ---------- merged prepack: all 11 weights in ONE launch ----------
// dst per weight: [nt][kt][lane][8 bf16]; W[k=kt*32+(lane>>4)*8+j][n=nt*16+(lane&15)]
struct PPDesc { const float* src; short* dst; int Ks, Ns, KT, NT, tile_base; };
struct PPArgs { PPDesc d[11]; int n_desc; int total_tiles; };

__global__ void prepack_all(PPArgs args) {
  int idx = blockIdx.x * 256 + threadIdx.x;
  int tile = idx >> 6;
  if (tile >= args.total_tiles) return;
  int lane = idx & 63;
  int e = 0;
  while (e + 1 < args.n_desc && args.d[e + 1].tile_base <= tile) ++e;
  const PPDesc D = args.d[e];
  int t = tile - D.tile_base;
  int kt = t % D.KT, nt = t / D.KT;
  int n = nt * 16 + (lane & 15);
  int kbase = kt * 32 + ((lane >> 4) * 8);
  short8v o;
#pragma unroll
  for (int j = 0; j < 8; ++j) {
    int k = kbase + j;
    o[j] = f2bf((k < D.Ks && n < D.Ns) ? D.src[k * D.Ns + n] : 0.f);
  }
  *(short8v*)&D.dst[((size_t)t * 64 + lane) * 8] = o;
}

// ---------- qb[b,c] = qst[b] @ Wg1[200:211] + bg1 (32 batches/block) ----------
__global__ void qb_kernel(const float* __restrict__ qst, const float* __restrict__ Wg1,
                          const float* __restrict__ bg1, float* __restrict__ qb) {
  int c = threadIdx.x;
  int b0 = blockIdx.x * 32;
  float wcol[11];
#pragma unroll
  for (int k = 0; k < 11; ++k) wcol[k] = Wg1[(200 + k) * 256 + c];
  float bias = bg1[c];
#pragma unroll 1
  for (int bb = 0; bb < 32; ++bb) {
    int b = b0 + bb;
    float acc = bias;
#pragma unroll
    for (int k = 0; k < 11; ++k) acc += qst[b * 11 + k] * wcol[k];
    qb[b * 256 + c] = acc;
  }
}

// ---------- encoder: tabs[64 rows x 10] -> x -> u,v (bf16, [obj][256]) ----------
__launch_bounds__(256, 3)
__global__ void enc_kernel(const float* __restrict__ tabs,
    const float* __restrict__ bi1, const float* __restrict__ bi2, const float* __restrict__ bi3,
    const short* __restrict__ Wi1p, const short* __restrict__ Wi2p, const short* __restrict__ Wi3p,
    const short* __restrict__ Wap, const short* __restrict__ Wbp,
    short* __restrict__ u_g, short* __restrict__ v_g) {
  __shared__ __align__(16) short sIn[64 * 40];   // K padded 10->32, stride 40
  __shared__ __align__(16) short sH1[64 * 256];  // swizzled; sX aliases after L2
  __shared__ __align__(16) short sH2[64 * 128];  // swizzled
  short* sX = sH1;
  const int tid = threadIdx.x;
  const int lane = tid & 63, w = tid >> 6, quad = lane >> 4, ll = lane & 15;
  const int xl = (ll & 7) << 3;
  const int obj0 = blockIdx.x * 64;

  for (int idx = tid; idx < 64 * 40; idx += 256) {
    int r = idx / 40, k = idx - r * 40;
    float v = (k < 10) ? tabs[(obj0 + r) * 10 + k] : 0.f;
    sIn[idx] = f2bf(v);
  }
  __syncthreads();

  // L1: K=32(pad), out 256. Wave owns 4 f-tiles, 4 obj-tiles.
  {
    f32x4 acc[4][4] = {};
    short8v bIn[4];
#pragma unroll
    for (int mt = 0; mt < 4; ++mt)
      bIn[mt] = *(const short8v*)&sIn[(mt * 16 + ll) * 40 + quad * 8];
#pragma unroll
    for (int ni = 0; ni < 4; ++ni) {
      short8v wf = *(const short8v*)&Wi1p[((w * 4 + ni) * 64 + lane) * 8];
#pragma unroll
      for (int mt = 0; mt < 4; ++mt) acc[mt][ni] = mfma16(wf, bIn[mt], acc[mt][ni]);
    }
#pragma unroll
    for (int ni = 0; ni < 4; ++ni) {
      int fbase = (w * 4 + ni) * 16 + quad * 4;
      f32x4 b4 = *(const f32x4*)&bi1[fbase];
#pragma unroll
      for (int mt = 0; mt < 4; ++mt) {
        int row = mt * 16 + ll;
        short4v o;
#pragma unroll
        for (int r = 0; r < 4; ++r) o[r] = f2bf(fmaxf(acc[mt][ni][r] + b4[r], 0.f));
        *(short4v*)&sH1[swz256(row, fbase)] = o;
      }
    }
  }
  __syncthreads();

  // L2: K=256, out 128. Wave owns 2 f-tiles.
  {
    f32x4 acc[4][2] = {};
#pragma unroll 1
    for (int kt = 0; kt < 8; ++kt) {
      short8v wf[2];
#pragma unroll
      for (int ni = 0; ni < 2; ++ni)
        wf[ni] = *(const short8v*)&Wi2p[(((w * 2 + ni) * 8 + kt) * 64 + lane) * 8];
#pragma unroll
      for (int mt = 0; mt < 4; ++mt) {
        short8v h = *(const short8v*)&sH1[(mt * 16 + ll) * 256 + ((kt * 32 + quad * 8) ^ xl)];
#pragma unroll
        for (int ni = 0; ni < 2; ++ni) acc[mt][ni] = mfma16(wf[ni], h, acc[mt][ni]);
      }
    }
    __syncthreads();   // sH1 reads done (sX aliases it)
#pragma unroll
    for (int ni = 0; ni < 2; ++ni) {
      int fbase = (w * 2 + ni) * 16 + quad * 4;
      f32x4 b4 = *(const f32x4*)&bi2[fbase];
#pragma unroll
      for (int mt = 0; mt < 4; ++mt) {
        int row = mt * 16 + ll;
        short4v o;
#pragma unroll
        for (int r = 0; r < 4; ++r) o[r] = f2bf(fmaxf(acc[mt][ni][r] + b4[r], 0.f));
        *(short4v*)&sH2[swz128(row, fbase)] = o;
      }
    }
  }
  __syncthreads();

  // L3: K=128, out 128 (cols>=100 zero), NO relu -> sX
  {
    f32x4 acc[4][2] = {};
#pragma unroll 1
    for (int kt = 0; kt < 4; ++kt) {
      short8v wf[2];
#pragma unroll
      for (int ni = 0; ni < 2; ++ni)
        wf[ni] = *(const short8v*)&Wi3p[(((w * 2 + ni) * 4 + kt) * 64 + lane) * 8];
#pragma unroll
      for (int mt = 0; mt < 4; ++mt) {
        short8v h = *(const short8v*)&sH2[(mt * 16 + ll) * 128 + ((kt * 32 + quad * 8) ^ xl)];
#pragma unroll
        for (int ni = 0; ni < 2; ++ni) acc[mt][ni] = mfma16(wf[ni], h, acc[mt][ni]);
      }
    }
#pragma unroll
    for (int ni = 0; ni < 2; ++ni) {
      int fbase = (w * 2 + ni) * 16 + quad * 4;
#pragma unroll
      for (int mt = 0; mt < 4; ++mt) {
        int row = mt * 16 + ll;
        short4v o;
#pragma unroll
        for (int r = 0; r < 4; ++r) {
          int f = fbase + r;
          float vv = (f < 100) ? (acc[mt][ni][r] + bi3[f]) : 0.f;
          o[r] = f2bf(vv);
        }
        *(short4v*)&sX[swz128(row, fbase)] = o;
      }
    }
  }
  __syncthreads();

  // L4: u = x @ Wa ; v = x @ Wb  K=128, out 256 each, no bias/relu
#pragma unroll 1
  for (int pass = 0; pass < 2; ++pass) {
    const short* Wp = pass ? Wbp : Wap;
    short* outg = pass ? v_g : u_g;
    f32x4 acc[4][4] = {};
#pragma unroll 1
    for (int kt = 0; kt < 4; ++kt) {
      short8v wf[4];
#pragma unroll
      for (int ni = 0; ni < 4; ++ni)
        wf[ni] = *(const short8v*)&Wp[(((w * 4 + ni) * 4 + kt) * 64 + lane) * 8];
#pragma unroll
      for (int mt = 0; mt < 4; ++mt) {
        short8v h = *(const short8v*)&sX[(mt * 16 + ll) * 128 + ((kt * 32 + quad * 8) ^ xl)];
#pragma unroll
        for (int ni = 0; ni < 4; ++ni) acc[mt][ni] = mfma16(wf[ni], h, acc[mt][ni]);
      }
    }
#pragma unroll
    for (int ni = 0; ni < 4; ++ni) {
      int fbase = (w * 4 + ni) * 16 + quad * 4;
#pragma unroll
      for (int mt = 0; mt < 4; ++mt) {
        int obj = obj0 + mt * 16 + ll;
        short4v o;
#pragma unroll
        for (int r = 0; r < 4; ++r) o[r] = f2bf(acc[mt][ni][r]);
        *(short4v*)&outg[(size_t)obj * 256 + fbase] = o;   // 8B coalesced store
      }
    }
  }
}

// ---------- pair layer: one 256-out GEMM over 80 rows (72 real), templated epilogue ----
// Called 3x from pair_kernel (no L-dependent pointer phis — r7 crash hedge).
template<int LAST>
__device__ __forceinline__ void pair_layer(short* sH,
    const short* __restrict__ Wp, const float* __restrict__ bp,
    float* __restrict__ g_g, int b0, int w, int lane, int quad, int ll, int xl) {
  f32x4 acc[5][4] = {};
#pragma unroll 1
  for (int kt = 0; kt < 8; ++kt) {
    short8v wf[4];
#pragma unroll
    for (int ni = 0; ni < 4; ++ni)
      wf[ni] = *(const short8v*)&Wp[(((w * 4 + ni) * 8 + kt) * 64 + lane) * 8];
#pragma unroll
    for (int mt = 0; mt < 5; ++mt) {
      short8v h = *(const short8v*)&sH[(mt * 16 + ll) * 256 + ((kt * 32 + quad * 8) ^ xl)];
#pragma unroll
      for (int ni = 0; ni < 4; ++ni) acc[mt][ni] = mfma16(wf[ni], h, acc[mt][ni]);
    }
  }
  __syncthreads();  // all reads of sH done before in-place overwrite
  if (!LAST) {
#pragma unroll
    for (int ni = 0; ni < 4; ++ni) {
      int fbase = (w * 4 + ni) * 16 + quad * 4;
      f32x4 b4 = *(const f32x4*)&bp[fbase];
#pragma unroll
      for (int mt = 0; mt < 5; ++mt) {
        int p = mt * 16 + ll;
        short4v o;
#pragma unroll
        for (int r = 0; r < 4; ++r) o[r] = f2bf(fmaxf(acc[mt][ni][r] + b4[r], 0.f));
        *(short4v*)&sH[swz256(p, fbase)] = o;   // 8B write, 2-way bank = free
      }
    }
    __syncthreads();
  } else {
    // g4: relu + sum-pool. lane ll = row within tile; butterfly over ll bits (d=1..8);
    // ll==0 lane of each quad stores its f-quad straight to global. No pool LDS.
#pragma unroll
    for (int ni = 0; ni < 4; ++ni) {
      int fbase = (w * 4 + ni) * 16 + quad * 4;
      f32x4 b4 = *(const f32x4*)&bp[fbase];
      f32x4 s0 = {0.f, 0.f, 0.f, 0.f}, s1 = {0.f, 0.f, 0.f, 0.f};
#pragma unroll
      for (int mt = 0; mt < 5; ++mt) {
        int p = mt * 16 + ll;
#pragma unroll
        for (int r = 0; r < 4; ++r) {
          float v = fmaxf(acc[mt][ni][r] + b4[r], 0.f);
          if (p < 36) s0[r] += v;
          else if (p < 72) s1[r] += v;
        }
      }
#pragma unroll
      for (int d = 1; d <= 8; d <<= 1) {
#pragma unroll
        for (int r = 0; r < 4; ++r) {
          s0[r] += __shfl_xor(s0[r], d, 64);
          s1[r] += __shfl_xor(s1[r], d, 64);
        }
      }
      if (ll == 0) {
        *(f32x4*)&g_g[(size_t)b0 * 256 + fbase] = s0;
        *(f32x4*)&g_g[(size_t)(b0 + 1) * 256 + fbase] = s1;
      }
    }
  }
}

// ---------- pair MLP: 256 thr (4 waves), 2 batches/block, 72 rows (pad->80) ----------
// BALANCED weight-stationary: each wave owns 4 f-tiles (ni=4) and ALL 5 m-tiles.
// acc[5][4]=80 AGPR + ~60 VGPR fits (256,3)=170 budget (r2 precedent).
// LDS 41.5 KB -> 3 blocks/CU = 12 waves. Weight bytes read once per block/layer.
__launch_bounds__(256, 3)
__global__ void pair_kernel(const short* __restrict__ u_g, const short* __restrict__ v_g,
    const float* __restrict__ qbp,
    const short* __restrict__ Wg2p, const short* __restrict__ Wg3p, const short* __restrict__ Wg4p,
    const float* __restrict__ bg2, const float* __restrict__ bg3, const float* __restrict__ bg4,
    float* __restrict__ g_g) {
  __shared__ __align__(16) short sH[81 * 256];   // 41,472 B (row 80 = slack, rows 72..79 pad)
  const int tid = threadIdx.x;
  const int lane = tid & 63, w = tid >> 6, quad = lane >> 4, ll = lane & 15;
  const int xl = (ll & 7) << 3;
  const int b0 = blockIdx.x * 2;

  // zero pad rows 72..80 (2304 shorts = 256 thr x 9)
  *(short8v*)&sH[72 * 256 + tid * 8] = short8v{0, 0, 0, 0, 0, 0, 0, 0};
  if (tid < 32) *(short8v*)&sH[80 * 256 + tid * 8] = short8v{0, 0, 0, 0, 0, 0, 0, 0};

  // h1 = relu(u[j] + v[i] + qb): one 16B chunk per thread; 72 rows x 32 chunks = 2304 = 9*256.
#pragma unroll 1
  for (int it = 0; it < 9; ++it) {
    int vi = it * 256 + tid;
    int row = vi >> 5, c8 = (vi & 31) * 8;
    int bb = row / 36, p = row - bb * 36;
    int i2 = p / 6, j2 = p - i2 * 6;
    short8v u8 = *(const short8v*)&u_g[((b0 + bb) * 6 + j2) * 256 + c8];
    short8v v8 = *(const short8v*)&v_g[((b0 + bb) * 6 + i2) * 256 + c8];
    f32x4 qa = *(const f32x4*)&qbp[(b0 + bb) * 256 + c8];
    f32x4 qc = *(const f32x4*)&qbp[(b0 + bb) * 256 + c8 + 4];
    short8v o;
#pragma unroll
    for (int e = 0; e < 4; ++e)
      o[e] = f2bf(fmaxf(bf2f(u8[e]) + bf2f(v8[e]) + qa[e], 0.f));
#pragma unroll
    for (int e = 0; e < 4; ++e)
      o[4 + e] = f2bf(fmaxf(bf2f(u8[4 + e]) + bf2f(v8[4 + e]) + qc[e], 0.f));
    *(short8v*)&sH[row * 256 + (c8 ^ ((row & 7) << 3))] = o;
  }
  __syncthreads();

  pair_layer<0>(sH, Wg2p, bg2, g_g, b0, w, lane, quad, ll, xl);
  pair_layer<0>(sH, Wg3p, bg3, g_g, b0, w, lane, quad, ll, xl);
  pair_layer<1>(sH, Wg4p, bg4, g_g, b0, w, lane, quad, ll, xl);
}

// ---------- head helper (transposed): 64x256 @ 256x256 + bias + relu, LDS->LDS ----------
__device__ __forceinline__ void gemm64x256T(const short* sInp, short* sOut,
    const short* __restrict__ Wp, const float* __restrict__ bias,
    int w, int lane, int quad, int ll, int xl) {
  f32x4 acc[4][4] = {};
#pragma unroll 1
  for (int kt = 0; kt < 8; ++kt) {
    short8v wf[4];
#pragma unroll
    for (int ni = 0; ni < 4; ++ni)
      wf[ni] = *(const short8v*)&Wp[(((w * 4 + ni) * 8 + kt) * 64 + lane) * 8];
#pragma unroll
    for (int mt = 0; mt < 4; ++mt) {
      short8v h = *(const short8v*)&sInp[(mt * 16 + ll) * 256 + ((kt * 32 + quad * 8) ^ xl)];
#pragma unroll
      for (int ni = 0; ni < 4; ++ni) acc[mt][ni] = mfma16(wf[ni], h, acc[mt][ni]);
    }
  }
#pragma unroll
  for (int ni = 0; ni < 4; ++ni) {
    int fbase = (w * 4 + ni) * 16 + quad * 4;
    f32x4 b4 = *(const f32x4*)&bias[fbase];
#pragma unroll
    for (int mt = 0; mt < 4; ++mt) {
      int row = mt * 16 + ll;
      short4v o;
#pragma unroll
      for (int r = 0; r < 4; ++r) o[r] = f2bf(fmaxf(acc[mt][ni][r] + b4[r], 0.f));
      *(short4v*)&sOut[swz256(row, fbase)] = o;
    }
  }
}

// ---------- head: g -> f -> o -> logits -> log_softmax ----------
__launch_bounds__(256, 2)
__global__ void head_kernel(const float* __restrict__ g_g,
    const short* __restrict__ Wfp, const float* __restrict__ bf_,
    const short* __restrict__ Wo1p, const float* __restrict__ bo1,
    const short* __restrict__ Wo2p, const float* __restrict__ bo2,
    float* __restrict__ outp) {
  __shared__ __align__(16) short sA[64 * 256];
  __shared__ __align__(16) short sB[64 * 256];
  __shared__ __align__(16) float sL[64 * 16];
  const int tid = threadIdx.x;
  const int lane = tid & 63, w = tid >> 6, quad = lane >> 4, ll = lane & 15;
  const int xl = (ll & 7) << 3;
  const int b0 = blockIdx.x * 64;

#pragma unroll 1
  for (int it = 0; it < 16; ++it) {
    int vi = it * 256 + tid;
    int row = vi >> 6, c4 = (vi & 63) * 4;
    f32x4 gv = *(const f32x4*)&g_g[(b0 + row) * 256 + c4];
    short4v o;
#pragma unroll
    for (int e = 0; e < 4; ++e) o[e] = f2bf(gv[e]);
    *(short4v*)&sA[row * 256 + (c4 ^ ((row & 7) << 3))] = o;
  }
  __syncthreads();
  gemm64x256T(sA, sB, Wfp, bf_, w, lane, quad, ll, xl);
  __syncthreads();
  gemm64x256T(sB, sA, Wo1p, bo1, w, lane, quad, ll, xl);
  __syncthreads();
  {
    // Wo2: wave w owns batch tile w; lane ll = batch, regs = classes.
    f32x4 acc = {};
#pragma unroll 1
    for (int kt = 0; kt < 8; ++kt) {
      short8v wf = *(const short8v*)&Wo2p[(kt * 64 + lane) * 8];
      short8v h = *(const short8v*)&sA[(w * 16 + ll) * 256 + ((kt * 32 + quad * 8) ^ xl)];
      acc = mfma16(wf, h, acc);
    }
    f32x4 ov;
#pragma unroll
    for (int r = 0; r < 4; ++r) {
      int cls = quad * 4 + r;
      ov[r] = acc[r] + ((cls < 10) ? bo2[cls] : 0.f);
    }
    *(f32x4*)&sL[(w * 16 + ll) * 16 + quad * 4] = ov;   // b128 store
  }
  __syncthreads();
  if (tid < 64) {
    float m = -1e30f;
#pragma unroll
    for (int c = 0; c < 10; ++c) m = fmaxf(m, sL[tid * 16 + c]);
    float s = 0.f;
#pragma unroll
    for (int c = 0; c < 10; ++c) s += expf(sL[tid * 16 + c] - m);
    float ls = logf(s) + m;
#pragma unroll
    for (int c = 0; c < 10; ++c) outp[(b0 + tid) * 10 + c] = sL[tid * 16 + c] - ls;
  }
}

extern "C" void kernel_launch(void* const* d_in, const int* in_sizes, int n_in,
                              void* d_out, int out_size, void* d_ws, size_t ws_size,
                              hipStream_t stream) {
  const float* tabs = (const float*)d_in[0];
  const float* qst  = (const float*)d_in[1];
  const float* Wi1 = (const float*)d_in[2];  const float* bi1 = (const float*)d_in[3];
  const float* Wi2 = (const float*)d_in[4];  const float* bi2 = (const float*)d_in[5];
  const float* Wi3 = (const float*)d_in[6];  const float* bi3 = (const float*)d_in[7];
  const float* Wg1 = (const float*)d_in[8];  const float* bg1 = (const float*)d_in[9];
  const float* Wg2 = (const float*)d_in[10]; const float* bg2 = (const float*)d_in[11];
  const float* Wg3 = (const float*)d_in[12]; const float* bg3 = (const float*)d_in[13];
  const float* Wg4 = (const float*)d_in[14]; const float* bg4 = (const float*)d_in[15];
  const float* Wf  = (const float*)d_in[16]; const float* bf_ = (const float*)d_in[17];
  const float* Wo1 = (const float*)d_in[18]; const float* bo1 = (const float*)d_in[19];
  const float* Wo2 = (const float*)d_in[20]; const float* bo2 = (const float*)d_in[21];
  float* outp = (float*)d_out;
  (void)in_sizes; (void)n_in; (void)out_size; (void)ws_size;

  char* ws = (char*)d_ws;
  size_t off = 0;
  // +4 KB slack per buffer: no wide access can land exactly on an allocation edge.
  auto alloc = [&](size_t bytes) {
    void* p = ws + off; off += (bytes + 4096 + 255) & ~(size_t)255; return p;
  };
  const size_t BN = 16384ull * 6;
  short* u_g = (short*)alloc(BN * 256 * 2);
  short* v_g = (short*)alloc(BN * 256 * 2);
  float* qb  = (float*)alloc(16384ull * 256 * 4);
  float* g_g = (float*)alloc(16384ull * 256 * 4);
  short* Wi1p = (short*)alloc(16 * 1 * 64 * 8 * 2);
  short* Wi2p = (short*)alloc(8 * 8 * 64 * 8 * 2);
  short* Wi3p = (short*)alloc(8 * 4 * 64 * 8 * 2);
  short* Wap  = (short*)alloc(16 * 4 * 64 * 8 * 2);
  short* Wbp  = (short*)alloc(16 * 4 * 64 * 8 * 2);
  short* Wg2p = (short*)alloc(16 * 8 * 64 * 8 * 2);
  short* Wg3p = (short*)alloc(16 * 8 * 64 * 8 * 2);
  short* Wg4p = (short*)alloc(16 * 8 * 64 * 8 * 2);
  short* Wfp  = (short*)alloc(16 * 8 * 64 * 8 * 2);
  short* Wo1p = (short*)alloc(16 * 8 * 64 * 8 * 2);
  short* Wo2p = (short*)alloc(1 * 8 * 64 * 8 * 2);

  PPArgs pa;
  int tb = 0, nd = 0;
  auto add = [&](const float* src, short* dst, int Ks, int Ns, int KT, int NT) {
    pa.d[nd++] = PPDesc{src, dst, Ks, Ns, KT, NT, tb};
    tb += KT * NT;
  };
  add(Wi1, Wi1p, 10, 256, 1, 16);
  add(Wi2, Wi2p, 256, 128, 8, 8);
  add(Wi3, Wi3p, 128, 100, 4, 8);
  add(Wg1,             Wap, 100, 256, 4, 16);
  add(Wg1 + 100 * 256, Wbp, 100, 256, 4, 16);
  add(Wg2, Wg2p, 256, 256, 8, 16);
  add(Wg3, Wg3p, 256, 256, 8, 16);
  add(Wg4, Wg4p, 256, 256, 8, 16);
  add(Wf,  Wfp,  256, 256, 8, 16);
  add(Wo1, Wo1p, 256, 256, 8, 16);
  add(Wo2, Wo2p, 256, 10, 8, 1);
  pa.n_desc = nd;
  pa.total_tiles = tb;
  prepack_all<<<(tb * 64 + 255) / 256, 256, 0, stream>>>(pa);

  qb_kernel<<<512, 256, 0, stream>>>(qst, Wg1, bg1, qb);
  enc_kernel<<<1536, 256, 0, stream>>>(tabs, bi1, bi2, bi3, Wi1p, Wi2p, Wi3p, Wap, Wbp, u_g, v_g);
  pair_kernel<<<8192, 256, 0, stream>>>(u_g, v_g, qb, Wg2p, Wg3p, Wg4p, bg2, bg3, bg4, g_g);
  head_kernel<<<256, 256, 0, stream>>>(g_g, Wfp, bf_, Wo1p, bo1, Wo2p, bo2, outp);
}